// Round 16
// baseline (126.965 us; speedup 1.0000x reference)
//
#include <hip/hip_runtime.h>
#include <math.h>

#define NB    32768
#define DDIM  64
#define HDIM  512
#define PDIM  23        // 3*K - 1
#define KBINS 8
#define BM    64
#define NCOLS (DDIM * PDIM)   // 1472
#define CHUNK 368             // 23 n-tiles of 16 = 16 d's worth of params
#define PSTRIDE 372           // f32 per pstage row (368 + pad)
#define NTILES 92             // NCOLS / 16

#define RQ_BOUND  4.0f
#define RQ_MINBIN 0.001f
#define RQ_MINDER 0.001f

typedef __attribute__((ext_vector_type(8))) _Float16 half8;
typedef __attribute__((ext_vector_type(4))) float f32x4;
typedef unsigned short ushort_t;

// ---------------------------------------------------------------------------
// prep (validated R10/R12): masks + fp16 + MFMA-fragment-major layout.
// ---------------------------------------------------------------------------
__global__ __launch_bounds__(256) void prep_frag(const float* __restrict__ W1,
                                                 const float* __restrict__ W2,
                                                 _Float16* __restrict__ W1g,
                                                 _Float16* __restrict__ W2g) {
    const int gid = blockIdx.x * 256 + threadIdx.x;
    const int NW1 = 32 * 2 * 64;            // 4096 fragment-groups for W1
    if (gid < NW1) {
        const int lane = gid & 63;
        const int tk   = gid >> 6;          // htile*2 + kt
        const int kt   = tk & 1, ht = tk >> 1;
        const int h = ht * 16 + (lane & 15);
        const int k = kt * 32 + (lane >> 4) * 8;
        const float* src = W1 + h * DDIM + k;
        const int hm63 = h % 63;
        half8 v;
        #pragma unroll
        for (int e = 0; e < 8; ++e)
            v[e] = (_Float16)(((k + e) <= hm63) ? src[e] : 0.0f);
        *(half8*)(W1g + (size_t)gid * 8) = v;
    } else {
        const int g2 = gid - NW1;
        if (g2 < NTILES * 16 * 64) {
            const int lane = g2 & 63;
            const int tk   = g2 >> 6;       // T*16 + kt
            const int kt   = tk & 15, T = tk >> 4;
            const int col  = T * 16 + (lane & 15);
            const int k    = kt * 32 + (lane >> 4) * 8;
            const float* src = W2 + (size_t)col * HDIM + k;
            const int d = col / PDIM;
            half8 v;
            #pragma unroll
            for (int e = 0; e < 8; ++e)
                v[e] = (_Float16)((d > ((k + e) % 63)) ? src[e] : 0.0f);
            *(half8*)(W2g + (size_t)g2 * 8) = v;
        }
    }
}

__device__ __forceinline__ float fexp(float v)  { return __expf(v); }
__device__ __forceinline__ float flog(float v)  { return __logf(v); }
__device__ __forceinline__ float fdiv(float a, float b) { return __fdividef(a, b); }

// ---------------------------------------------------------------------------
// fused kernel R16: BM=64 (halves W2 L2 delivery — the dominant pipe) with the
// R15 MERGED schedule (kt-loop of chunk c+1 interleaved with spline of chunk c
// in one scheduling region) to neutralize the 1-block/CU lockstep that sank
// R11. 1024 threads, 16 waves; waves 0-6 own 2 W2 tiles, 7-15 own 1 (zero
// load redundancy). LDS = 64KB hm + 95.2KB pstage = 160768 B (R11-proven).
// Math bit-identical to R12/R15 (absmax 0.875).
// ---------------------------------------------------------------------------
__global__ __launch_bounds__(1024, 4) void fused_flow(
    const float* __restrict__ x,  const float* __restrict__ b1,
    const float* __restrict__ b2, const _Float16* __restrict__ W1g,
    const _Float16* __restrict__ W2g,
    float* __restrict__ z_out, float* __restrict__ ld_out)
{
    __shared__ __align__(16) ushort_t hm[BM * 512];      // 64 KB fp16, swizzled
    __shared__ __align__(16) float pstage[BM * PSTRIDE]; // 95.2 KB

    const int t    = threadIdx.x;
    const int row0 = blockIdx.x * BM;
    const int wv   = t >> 6;          // 0..15
    const int lane = t & 63;
    const int l15  = lane & 15;
    const int lg   = lane >> 4;

    char* hmB = (char*)hm;

    // ---- phase 1: GEMM1 (R11 verbatim, validated) ----
    {
        f32x4 acc1[2][4];
        #pragma unroll
        for (int j = 0; j < 2; ++j)
            #pragma unroll
            for (int m = 0; m < 4; ++m) acc1[j][m] = (f32x4){0.f, 0.f, 0.f, 0.f};

        #pragma unroll
        for (int kt = 0; kt < 2; ++kt) {
            half8 a[4];
            #pragma unroll
            for (int m = 0; m < 4; ++m) {
                const float* xr = x + (size_t)(row0 + m * 16 + l15) * DDIM + kt * 32 + lg * 8;
                const float4 xa = *(const float4*)(xr);
                const float4 xb = *(const float4*)(xr + 4);
                a[m][0] = (_Float16)xa.x; a[m][1] = (_Float16)xa.y;
                a[m][2] = (_Float16)xa.z; a[m][3] = (_Float16)xa.w;
                a[m][4] = (_Float16)xb.x; a[m][5] = (_Float16)xb.y;
                a[m][6] = (_Float16)xb.z; a[m][7] = (_Float16)xb.w;
            }
            #pragma unroll
            for (int j = 0; j < 2; ++j) {
                const int ht = wv * 2 + j;
                const half8 b = *(const half8*)(W1g + (size_t)ht * 1024 + kt * 512 + lane * 8);
                #pragma unroll
                for (int m = 0; m < 4; ++m)
                    acc1[j][m] = __builtin_amdgcn_mfma_f32_16x16x32_f16(a[m], b, acc1[j][m], 0, 0, 0);
            }
        }
        #pragma unroll
        for (int j = 0; j < 2; ++j) {
            const int h = (wv * 2 + j) * 16 + l15;
            const float bias = b1[h];
            #pragma unroll
            for (int m = 0; m < 4; ++m) {
                #pragma unroll
                for (int q = 0; q < 4; ++q) {
                    const int r = m * 16 + lg * 4 + q;
                    const _Float16 hv = (_Float16)fmaxf(acc1[j][m][q] + bias, 0.0f);
                    *(ushort_t*)(hmB + r * 1024 + ((h * 2) ^ ((r & 7) << 4))) =
                        __builtin_bit_cast(ushort_t, hv);
                }
            }
        }
    }
    __syncthreads();

    // ---- phase 2: merged software-pipelined chunks ----
    float ldacc = 0.0f;
    const int srow = t >> 4;   // 0..63
    const int sd   = t & 15;   // 0..15
    const bool two = (wv < 7); // wave owns a second tile (16+wv)?
    const float CNORM = 1.0f - RQ_MINBIN * KBINS;

    const _Float16* w2base[2];
    w2base[0] = W2g + (size_t)wv * 8192 + lane * 8;
    w2base[1] = W2g + (size_t)(two ? 16 + wv : 22) * 8192 + lane * 8;

    f32x4 acc[2][4];
    float xk[KBINS + 1], yk[KBINS + 1], dv[KBINS + 1];

#define ZERO_ACC                                                            \
    _Pragma("unroll")                                                       \
    for (int i = 0; i < 2; ++i)                                             \
        _Pragma("unroll")                                                   \
        for (int m = 0; m < 4; ++m) acc[i][m] = (f32x4){0.f, 0.f, 0.f, 0.f};

// one 4-kt group of chunk CN: 4 LDS A-frags + 1-2 coalesced B-frags + 4-8 MFMA/kt
#define KTG(CN, K0)                                                         \
    {                                                                       \
        const size_t coff = (size_t)(CN) * (23 * 8192);                     \
        _Pragma("unroll")                                                   \
        for (int kt = (K0); kt < (K0) + 4; ++kt) {                          \
            half8 ah[4];                                                    \
            _Pragma("unroll")                                               \
            for (int m = 0; m < 4; ++m) {                                   \
                const int r  = m * 16 + l15;                                \
                const int kb = (kt * 32 + lg * 8) * 2;                      \
                ah[m] = *(const half8*)(hmB + r * 1024 + (kb ^ ((r & 7) << 4))); \
            }                                                               \
            const half8 b0 = *(const half8*)(w2base[0] + coff + kt * 512);  \
            _Pragma("unroll")                                               \
            for (int m = 0; m < 4; ++m)                                     \
                acc[0][m] = __builtin_amdgcn_mfma_f32_16x16x32_f16(ah[m], b0, acc[0][m], 0, 0, 0); \
            if (two) {                                                      \
                const half8 b1f = *(const half8*)(w2base[1] + coff + kt * 512); \
                _Pragma("unroll")                                           \
                for (int m = 0; m < 4; ++m)                                 \
                    acc[1][m] = __builtin_amdgcn_mfma_f32_16x16x32_f16(ah[m], b1f, acc[1][m], 0, 0, 0); \
            }                                                               \
        }                                                                   \
    }

#define STAGE(CN)                                                           \
    {                                                                       \
        const int lc0 = wv * 16 + l15;                                      \
        _Pragma("unroll")                                                   \
        for (int m = 0; m < 4; ++m)                                         \
            _Pragma("unroll")                                               \
            for (int q = 0; q < 4; ++q)                                     \
                pstage[(m * 16 + lg * 4 + q) * PSTRIDE + lc0] = acc[0][m][q]; \
        if (two) {                                                          \
            const int lc1 = (16 + wv) * 16 + l15;                           \
            _Pragma("unroll")                                               \
            for (int m = 0; m < 4; ++m)                                     \
                _Pragma("unroll")                                           \
                for (int q = 0; q < 4; ++q)                                 \
                    pstage[(m * 16 + lg * 4 + q) * PSTRIDE + lc1] = acc[1][m][q]; \
        }                                                                   \
    }

#define SPL_A(CS)                                                           \
    {                                                                       \
        const float* pp = &pstage[srow * PSTRIDE + sd * PDIM];              \
        const float* bp = b2 + (size_t)((CS) * 16 + sd) * PDIM;             \
        float e[8]; float s = 0.0f;                                         \
        _Pragma("unroll")                                                   \
        for (int i = 0; i < 8; ++i) { e[i] = fexp(pp[i] + bp[i]); s += e[i]; } \
        const float cinv = CNORM * fdiv(1.0f, s);                           \
        float cum = 0.0f;                                                   \
        xk[0] = -RQ_BOUND;                                                  \
        _Pragma("unroll")                                                   \
        for (int i = 0; i < 8; ++i) {                                       \
            cum += fmaf(e[i], cinv, RQ_MINBIN);                             \
            xk[i + 1] = fmaf(cum, 2.0f * RQ_BOUND, -RQ_BOUND);              \
        }                                                                   \
        xk[KBINS] = RQ_BOUND;                                               \
    }

#define SPL_B(CS)                                                           \
    {                                                                       \
        const float* pp = &pstage[srow * PSTRIDE + sd * PDIM];              \
        const float* bp = b2 + (size_t)((CS) * 16 + sd) * PDIM;             \
        float e[8]; float s = 0.0f;                                         \
        _Pragma("unroll")                                                   \
        for (int i = 0; i < 8; ++i) { e[i] = fexp(pp[8 + i] + bp[8 + i]); s += e[i]; } \
        const float cinv = CNORM * fdiv(1.0f, s);                           \
        float cum = 0.0f;                                                   \
        yk[0] = -RQ_BOUND;                                                  \
        _Pragma("unroll")                                                   \
        for (int i = 0; i < 8; ++i) {                                       \
            cum += fmaf(e[i], cinv, RQ_MINBIN);                             \
            yk[i + 1] = fmaf(cum, 2.0f * RQ_BOUND, -RQ_BOUND);              \
        }                                                                   \
        yk[KBINS] = RQ_BOUND;                                               \
    }

#define SPL_C(CS)                                                           \
    {                                                                       \
        const float* pp = &pstage[srow * PSTRIDE + sd * PDIM];              \
        const float* bp = b2 + (size_t)((CS) * 16 + sd) * PDIM;             \
        dv[0] = 1.0f;                                                       \
        _Pragma("unroll")                                                   \
        for (int i = 0; i < 7; ++i)                                         \
            dv[i + 1] = RQ_MINDER + flog(1.0f + fexp(pp[16 + i] + bp[16 + i])); \
        dv[KBINS] = 1.0f;                                                   \
    }

#define SPL_D(CS)                                                           \
    {                                                                       \
        const int dcol = (CS) * 16 + sd;                                    \
        const float xorig = x[(size_t)(row0 + srow) * DDIM + dcol];         \
        const float xc = fminf(fmaxf(xorig, -RQ_BOUND), RQ_BOUND);          \
        const bool inside = (xorig >= -RQ_BOUND) && (xorig <= RQ_BOUND);    \
        int idx = 0;                                                        \
        _Pragma("unroll")                                                   \
        for (int i = 1; i < KBINS; ++i) idx += (xc >= xk[i]) ? 1 : 0;       \
        float x_k = xk[0], x_k1 = xk[1];                                    \
        float y_k = yk[0], y_k1 = yk[1];                                    \
        float d_k = dv[0], d_k1 = dv[1];                                    \
        _Pragma("unroll")                                                   \
        for (int i = 1; i < KBINS; ++i) {                                   \
            const bool mm = (idx == i);                                     \
            x_k  = mm ? xk[i]     : x_k;                                    \
            x_k1 = mm ? xk[i + 1] : x_k1;                                   \
            y_k  = mm ? yk[i]     : y_k;                                    \
            y_k1 = mm ? yk[i + 1] : y_k1;                                   \
            d_k  = mm ? dv[i]     : d_k;                                    \
            d_k1 = mm ? dv[i + 1] : d_k1;                                   \
        }                                                                   \
        const float w_k = x_k1 - x_k;                                       \
        const float h_k = y_k1 - y_k;                                       \
        const float rw  = fdiv(1.0f, w_k);                                  \
        const float sv  = h_k * rw;                                         \
        const float th  = (xc - x_k) * rw;                                  \
        const float omt = 1.0f - th;                                        \
        const float t1m = th * omt;                                         \
        const float num = h_k * (sv * th * th + d_k * t1m);                 \
        const float den = sv + (d_k1 + d_k - 2.0f * sv) * t1m;              \
        const float yin = y_k + fdiv(num, den);                             \
        const float dnum = sv * sv * (d_k1 * th * th + 2.0f * sv * t1m + d_k * omt * omt); \
        const float ldin = flog(fdiv(dnum, den * den));                     \
        z_out[(size_t)(row0 + srow) * DDIM + dcol] = inside ? yin : xorig;  \
        ldacc += inside ? ldin : 0.0f;                                      \
    }

#define MERGED(CN, CS)                                                      \
    ZERO_ACC                                                                \
    KTG(CN, 0)  SPL_A(CS)                                                   \
    KTG(CN, 4)  SPL_B(CS)                                                   \
    KTG(CN, 8)  SPL_C(CS)                                                   \
    KTG(CN, 12) SPL_D(CS)

    // pipeline: KT(0) | STAGE(0) || [KT(c+1) ⋈ SPL(c)] | STAGE(c+1) || SPL(3)
    ZERO_ACC
    KTG(0, 0) KTG(0, 4) KTG(0, 8) KTG(0, 12)
    STAGE(0)
    __syncthreads();

    MERGED(1, 0)
    __syncthreads();
    STAGE(1)
    __syncthreads();

    MERGED(2, 1)
    __syncthreads();
    STAGE(2)
    __syncthreads();

    MERGED(3, 2)
    __syncthreads();
    STAGE(3)
    __syncthreads();

    SPL_A(3) SPL_B(3) SPL_C(3) SPL_D(3)

#undef MERGED
#undef SPL_D
#undef SPL_C
#undef SPL_B
#undef SPL_A
#undef STAGE
#undef KTG
#undef ZERO_ACC

    // ---- logdet: each row's 16 threads are consecutive lanes of one wave ----
    ldacc += __shfl_xor(ldacc, 1, 64);
    ldacc += __shfl_xor(ldacc, 2, 64);
    ldacc += __shfl_xor(ldacc, 4, 64);
    ldacc += __shfl_xor(ldacc, 8, 64);
    if (sd == 0) ld_out[row0 + srow] = ldacc;
}

// ---------------------------------------------------------------------------
extern "C" void kernel_launch(void* const* d_in, const int* in_sizes, int n_in,
                              void* d_out, int out_size, void* d_ws, size_t ws_size,
                              hipStream_t stream) {
    (void)in_sizes; (void)n_in; (void)out_size; (void)ws_size;
    const float* x  = (const float*)d_in[0];
    const float* W1 = (const float*)d_in[1];
    const float* b1 = (const float*)d_in[2];
    const float* W2 = (const float*)d_in[3];
    const float* b2 = (const float*)d_in[4];

    _Float16* W1g = (_Float16*)d_ws;                 // 32768 fp16 (frag-major)
    _Float16* W2g = W1g + HDIM * DDIM;               // 753664 fp16 (frag-major)
    float* z  = (float*)d_out;
    float* ld = z + (size_t)NB * DDIM;

    const int n_groups = 32 * 2 * 64 + NTILES * 16 * 64;   // 98304 fragment-groups
    prep_frag<<<(n_groups + 255) / 256, 256, 0, stream>>>(W1, W2, W1g, W2g);
    fused_flow<<<NB / BM, 1024, 0, stream>>>(x, b1, b2, W1g, W2g, z, ld);
}

// Round 17
// 90.434 us; speedup vs baseline: 1.4040x; 1.4040x over previous
//
#include <hip/hip_runtime.h>
#include <math.h>

#define NB    32768
#define DDIM  64
#define HDIM  512
#define PDIM  23        // 3*K - 1
#define KBINS 8
#define BM    32
#define NCOLS (DDIM * PDIM)   // 1472
#define CHUNK 368             // 23 n-tiles of 16 = 16 d's worth of params
#define PSTRIDE 372           // f32 per pstage row (368 + pad)
#define NTILES 92             // NCOLS / 16

#define RQ_BOUND  4.0f
#define RQ_MINBIN 0.001f
#define RQ_MINDER 0.001f

typedef __attribute__((ext_vector_type(8))) _Float16 half8;
typedef __attribute__((ext_vector_type(4))) float f32x4;
typedef unsigned short ushort_t;

// ---------------------------------------------------------------------------
// prep (validated R10/R12): masks + fp16 + MFMA-fragment-major layout.
// ---------------------------------------------------------------------------
__global__ __launch_bounds__(256) void prep_frag(const float* __restrict__ W1,
                                                 const float* __restrict__ W2,
                                                 _Float16* __restrict__ W1g,
                                                 _Float16* __restrict__ W2g) {
    const int gid = blockIdx.x * 256 + threadIdx.x;
    const int NW1 = 32 * 2 * 64;            // 4096 fragment-groups for W1
    if (gid < NW1) {
        const int lane = gid & 63;
        const int tk   = gid >> 6;          // htile*2 + kt
        const int kt   = tk & 1, ht = tk >> 1;
        const int h = ht * 16 + (lane & 15);
        const int k = kt * 32 + (lane >> 4) * 8;
        const float* src = W1 + h * DDIM + k;
        const int hm63 = h % 63;
        half8 v;
        #pragma unroll
        for (int e = 0; e < 8; ++e)
            v[e] = (_Float16)(((k + e) <= hm63) ? src[e] : 0.0f);
        *(half8*)(W1g + (size_t)gid * 8) = v;
    } else {
        const int g2 = gid - NW1;
        if (g2 < NTILES * 16 * 64) {
            const int lane = g2 & 63;
            const int tk   = g2 >> 6;       // T*16 + kt
            const int kt   = tk & 15, T = tk >> 4;
            const int col  = T * 16 + (lane & 15);
            const int k    = kt * 32 + (lane >> 4) * 8;
            const float* src = W2 + (size_t)col * HDIM + k;
            const int d = col / PDIM;
            half8 v;
            #pragma unroll
            for (int e = 0; e < 8; ++e)
                v[e] = (_Float16)((d > ((k + e) % 63)) ? src[e] : 0.0f);
            *(half8*)(W2g + (size_t)g2 * 8) = v;
        }
    }
}

__device__ __forceinline__ float fexp(float v)  { return __expf(v); }
__device__ __forceinline__ float flog(float v)  { return __logf(v); }
__device__ __forceinline__ float fdiv(float a, float b) { return __fdividef(a, b); }

// ---------------------------------------------------------------------------
// fused kernel R15 (validated best, 90.5µs): R12 barriered structure with
// kt-loop(c+1) and spline(c) MERGED into one scheduling region between the
// same barriers. Spline sliced into 4 independent sub-phases (xk/yk/dd/
// rational+z) interleaved between 4-kt groups so the scheduler fills MFMA &
// vmcnt stalls with spline VALU. absmax 0.875; traffic clean (10.4/8.3 MB).
// ---------------------------------------------------------------------------
__global__ __launch_bounds__(512, 4) void fused_flow(
    const float* __restrict__ x,  const float* __restrict__ b1,
    const float* __restrict__ b2, const _Float16* __restrict__ W1g,
    const _Float16* __restrict__ W2g,
    float* __restrict__ z_out, float* __restrict__ ld_out)
{
    __shared__ __align__(16) ushort_t hm[BM * 512];      // 32 KB fp16, swizzled
    __shared__ __align__(16) float pstage[BM * PSTRIDE]; // 46.5 KB

    const int t    = threadIdx.x;
    const int row0 = blockIdx.x * BM;
    const int wv   = t >> 6;
    const int lane = t & 63;
    const int l15  = lane & 15;
    const int lg   = lane >> 4;

    char* hmB = (char*)hm;

    // ---- phase 1: GEMM1 (identical to R12, validated) ----
    {
        f32x4 acc1[4][2];
        #pragma unroll
        for (int j = 0; j < 4; ++j)
            #pragma unroll
            for (int m = 0; m < 2; ++m) acc1[j][m] = (f32x4){0.f, 0.f, 0.f, 0.f};

        #pragma unroll
        for (int kt = 0; kt < 2; ++kt) {
            half8 a[2];
            #pragma unroll
            for (int m = 0; m < 2; ++m) {
                const float* xr = x + (size_t)(row0 + m * 16 + l15) * DDIM + kt * 32 + lg * 8;
                const float4 xa = *(const float4*)(xr);
                const float4 xb = *(const float4*)(xr + 4);
                a[m][0] = (_Float16)xa.x; a[m][1] = (_Float16)xa.y;
                a[m][2] = (_Float16)xa.z; a[m][3] = (_Float16)xa.w;
                a[m][4] = (_Float16)xb.x; a[m][5] = (_Float16)xb.y;
                a[m][6] = (_Float16)xb.z; a[m][7] = (_Float16)xb.w;
            }
            #pragma unroll
            for (int j = 0; j < 4; ++j) {
                const half8 b = *(const half8*)(W1g + (size_t)(wv * 4 + j) * 1024 + kt * 512 + lane * 8);
                #pragma unroll
                for (int m = 0; m < 2; ++m)
                    acc1[j][m] = __builtin_amdgcn_mfma_f32_16x16x32_f16(a[m], b, acc1[j][m], 0, 0, 0);
            }
        }
        #pragma unroll
        for (int j = 0; j < 4; ++j) {
            const int h = (wv * 4 + j) * 16 + l15;
            const float bias = b1[h];
            #pragma unroll
            for (int m = 0; m < 2; ++m) {
                #pragma unroll
                for (int q = 0; q < 4; ++q) {
                    const int r = m * 16 + lg * 4 + q;
                    const _Float16 hv = (_Float16)fmaxf(acc1[j][m][q] + bias, 0.0f);
                    *(ushort_t*)(hmB + r * 1024 + ((h * 2) ^ ((r & 7) << 4))) =
                        __builtin_bit_cast(ushort_t, hv);
                }
            }
        }
    }
    __syncthreads();

    // ---- phase 2: software-pipelined chunks ----
    float ldacc = 0.0f;
    const int srow = t >> 4;   // 0..31
    const int sd   = t & 15;   // 0..15
    const int tbase = wv * 3;
    const float CNORM = 1.0f - RQ_MINBIN * KBINS;

    const _Float16* w2base[3];
    #pragma unroll
    for (int i = 0; i < 3; ++i) {
        const int tile = (tbase + i < 23) ? (tbase + i) : 22;
        w2base[i] = W2g + (size_t)tile * 8192 + lane * 8;
    }

    f32x4 acc[3][2];
    float xk[KBINS + 1], yk[KBINS + 1], dv[KBINS + 1];

#define ZERO_ACC                                                            \
    _Pragma("unroll")                                                       \
    for (int i = 0; i < 3; ++i)                                             \
        _Pragma("unroll")                                                   \
        for (int m = 0; m < 2; ++m) acc[i][m] = (f32x4){0.f, 0.f, 0.f, 0.f};

// one 4-kt group of chunk CN: 2 LDS A-frags + 3 coalesced B-frags + 6 MFMA per kt
#define KTG(CN, K0)                                                         \
    {                                                                       \
        const size_t coff = (size_t)(CN) * (23 * 8192);                     \
        _Pragma("unroll")                                                   \
        for (int kt = (K0); kt < (K0) + 4; ++kt) {                          \
            half8 ah[2];                                                    \
            _Pragma("unroll")                                               \
            for (int m = 0; m < 2; ++m) {                                   \
                const int r  = m * 16 + l15;                                \
                const int kb = (kt * 32 + lg * 8) * 2;                      \
                ah[m] = *(const half8*)(hmB + r * 1024 + (kb ^ ((r & 7) << 4))); \
            }                                                               \
            half8 bfr[3];                                                   \
            _Pragma("unroll")                                               \
            for (int i = 0; i < 3; ++i)                                     \
                bfr[i] = *(const half8*)(w2base[i] + coff + kt * 512);      \
            _Pragma("unroll")                                               \
            for (int i = 0; i < 3; ++i)                                     \
                _Pragma("unroll")                                           \
                for (int m = 0; m < 2; ++m)                                 \
                    acc[i][m] = __builtin_amdgcn_mfma_f32_16x16x32_f16(ah[m], bfr[i], acc[i][m], 0, 0, 0); \
        }                                                                   \
    }

#define STAGE(CN)                                                           \
    _Pragma("unroll")                                                       \
    for (int i = 0; i < 3; ++i) {                                           \
        if (tbase + i < 23) {                                               \
            const int lcol = (tbase + i) * 16 + l15;                        \
            _Pragma("unroll")                                               \
            for (int m = 0; m < 2; ++m)                                     \
                _Pragma("unroll")                                           \
                for (int q = 0; q < 4; ++q)                                 \
                    pstage[(m * 16 + lg * 4 + q) * PSTRIDE + lcol] = acc[i][m][q]; \
        }                                                                   \
    }

// spline sub-phases for chunk CS (reads pstage staged last phase; independent
// of the concurrent KTG stream). Bit-identical math to R12's rqs_eval.
#define SPL_A(CS)                                                           \
    {                                                                       \
        const float* pp = &pstage[srow * PSTRIDE + sd * PDIM];              \
        const float* bp = b2 + (size_t)((CS) * 16 + sd) * PDIM;             \
        float e[8]; float s = 0.0f;                                         \
        _Pragma("unroll")                                                   \
        for (int i = 0; i < 8; ++i) { e[i] = fexp(pp[i] + bp[i]); s += e[i]; } \
        const float cinv = CNORM * fdiv(1.0f, s);                           \
        float cum = 0.0f;                                                   \
        xk[0] = -RQ_BOUND;                                                  \
        _Pragma("unroll")                                                   \
        for (int i = 0; i < 8; ++i) {                                       \
            cum += fmaf(e[i], cinv, RQ_MINBIN);                             \
            xk[i + 1] = fmaf(cum, 2.0f * RQ_BOUND, -RQ_BOUND);              \
        }                                                                   \
        xk[KBINS] = RQ_BOUND;                                               \
    }

#define SPL_B(CS)                                                           \
    {                                                                       \
        const float* pp = &pstage[srow * PSTRIDE + sd * PDIM];              \
        const float* bp = b2 + (size_t)((CS) * 16 + sd) * PDIM;             \
        float e[8]; float s = 0.0f;                                         \
        _Pragma("unroll")                                                   \
        for (int i = 0; i < 8; ++i) { e[i] = fexp(pp[8 + i] + bp[8 + i]); s += e[i]; } \
        const float cinv = CNORM * fdiv(1.0f, s);                           \
        float cum = 0.0f;                                                   \
        yk[0] = -RQ_BOUND;                                                  \
        _Pragma("unroll")                                                   \
        for (int i = 0; i < 8; ++i) {                                       \
            cum += fmaf(e[i], cinv, RQ_MINBIN);                             \
            yk[i + 1] = fmaf(cum, 2.0f * RQ_BOUND, -RQ_BOUND);              \
        }                                                                   \
        yk[KBINS] = RQ_BOUND;                                               \
    }

#define SPL_C(CS)                                                           \
    {                                                                       \
        const float* pp = &pstage[srow * PSTRIDE + sd * PDIM];              \
        const float* bp = b2 + (size_t)((CS) * 16 + sd) * PDIM;             \
        dv[0] = 1.0f;                                                       \
        _Pragma("unroll")                                                   \
        for (int i = 0; i < 7; ++i)                                         \
            dv[i + 1] = RQ_MINDER + flog(1.0f + fexp(pp[16 + i] + bp[16 + i])); \
        dv[KBINS] = 1.0f;                                                   \
    }

#define SPL_D(CS)                                                           \
    {                                                                       \
        const int dcol = (CS) * 16 + sd;                                    \
        const float xorig = x[(size_t)(row0 + srow) * DDIM + dcol];         \
        const float xc = fminf(fmaxf(xorig, -RQ_BOUND), RQ_BOUND);          \
        const bool inside = (xorig >= -RQ_BOUND) && (xorig <= RQ_BOUND);    \
        int idx = 0;                                                        \
        _Pragma("unroll")                                                   \
        for (int i = 1; i < KBINS; ++i) idx += (xc >= xk[i]) ? 1 : 0;       \
        float x_k = xk[0], x_k1 = xk[1];                                    \
        float y_k = yk[0], y_k1 = yk[1];                                    \
        float d_k = dv[0], d_k1 = dv[1];                                    \
        _Pragma("unroll")                                                   \
        for (int i = 1; i < KBINS; ++i) {                                   \
            const bool mm = (idx == i);                                     \
            x_k  = mm ? xk[i]     : x_k;                                    \
            x_k1 = mm ? xk[i + 1] : x_k1;                                   \
            y_k  = mm ? yk[i]     : y_k;                                    \
            y_k1 = mm ? yk[i + 1] : y_k1;                                   \
            d_k  = mm ? dv[i]     : d_k;                                    \
            d_k1 = mm ? dv[i + 1] : d_k1;                                   \
        }                                                                   \
        const float w_k = x_k1 - x_k;                                       \
        const float h_k = y_k1 - y_k;                                       \
        const float rw  = fdiv(1.0f, w_k);                                  \
        const float sv  = h_k * rw;                                         \
        const float th  = (xc - x_k) * rw;                                  \
        const float omt = 1.0f - th;                                        \
        const float t1m = th * omt;                                         \
        const float num = h_k * (sv * th * th + d_k * t1m);                 \
        const float den = sv + (d_k1 + d_k - 2.0f * sv) * t1m;              \
        const float yin = y_k + fdiv(num, den);                             \
        const float dnum = sv * sv * (d_k1 * th * th + 2.0f * sv * t1m + d_k * omt * omt); \
        const float ldin = flog(fdiv(dnum, den * den));                     \
        z_out[(size_t)(row0 + srow) * DDIM + dcol] = inside ? yin : xorig;  \
        ldacc += inside ? ldin : 0.0f;                                      \
    }

// merged region: chunk CN's kt-loop interleaved with chunk CS's spline
#define MERGED(CN, CS)                                                      \
    ZERO_ACC                                                                \
    KTG(CN, 0)  SPL_A(CS)                                                   \
    KTG(CN, 4)  SPL_B(CS)                                                   \
    KTG(CN, 8)  SPL_C(CS)                                                   \
    KTG(CN, 12) SPL_D(CS)

    // pipeline: KT(0) | STAGE(0) || [KT(c+1) ⋈ SPL(c)] | STAGE(c+1) || SPL(3)
    ZERO_ACC
    KTG(0, 0) KTG(0, 4) KTG(0, 8) KTG(0, 12)
    STAGE(0)
    __syncthreads();

    MERGED(1, 0)
    __syncthreads();
    STAGE(1)
    __syncthreads();

    MERGED(2, 1)
    __syncthreads();
    STAGE(2)
    __syncthreads();

    MERGED(3, 2)
    __syncthreads();
    STAGE(3)
    __syncthreads();

    SPL_A(3) SPL_B(3) SPL_C(3) SPL_D(3)

#undef MERGED
#undef SPL_D
#undef SPL_C
#undef SPL_B
#undef SPL_A
#undef STAGE
#undef KTG
#undef ZERO_ACC

    // ---- logdet: sum the 16 threads of each row ----
    ldacc += __shfl_xor(ldacc, 1, 64);
    ldacc += __shfl_xor(ldacc, 2, 64);
    ldacc += __shfl_xor(ldacc, 4, 64);
    ldacc += __shfl_xor(ldacc, 8, 64);
    if (sd == 0) ld_out[row0 + srow] = ldacc;
}

// ---------------------------------------------------------------------------
extern "C" void kernel_launch(void* const* d_in, const int* in_sizes, int n_in,
                              void* d_out, int out_size, void* d_ws, size_t ws_size,
                              hipStream_t stream) {
    (void)in_sizes; (void)n_in; (void)out_size; (void)ws_size;
    const float* x  = (const float*)d_in[0];
    const float* W1 = (const float*)d_in[1];
    const float* b1 = (const float*)d_in[2];
    const float* W2 = (const float*)d_in[3];
    const float* b2 = (const float*)d_in[4];

    _Float16* W1g = (_Float16*)d_ws;                 // 32768 fp16 (frag-major)
    _Float16* W2g = W1g + HDIM * DDIM;               // 753664 fp16 (frag-major)
    float* z  = (float*)d_out;
    float* ld = z + (size_t)NB * DDIM;

    const int n_groups = 32 * 2 * 64 + NTILES * 16 * 64;   // 98304 fragment-groups
    prep_frag<<<(n_groups + 255) / 256, 256, 0, stream>>>(W1, W2, W1g, W2g);
    fused_flow<<<NB / BM, 512, 0, stream>>>(x, b1, b2, W1g, W2g, z, ld);
}